// Round 11
// baseline (324.062 us; speedup 1.0000x reference)
//
#include <hip/hip_runtime.h>
#include <math.h>

// ---------------------------------------------------------------------------
// Problem constants (fixed production sizes from the reference)
// ---------------------------------------------------------------------------
namespace {
constexpr int cB  = 64;
constexpr int cNQ = 32;
constexpr int cND = 512;
constexpr int cNd = cB * cND;   // 32768
constexpr int cNq = cB * cNQ;   // 2048
constexpr int cEd = cNd * 8;    // 262144 (exactly 4096 per graph, graph-sorted)
constexpr int cEq = cNq * 8;    // 16384  (exactly 256 per graph, graph-sorted)
constexpr int LD_STRIDE = 516;
// front kernel block ranges: CSR first (starts immediately), then cvt/transpose
constexpr int NB_CSRD = 64;                    // [0,64)
constexpr int NB_CSRQ = 8;                     // [64,72)
constexpr int CVT0 = NB_CSRD + NB_CSRQ;        // 72
constexpr int NB_CVT = 2188;                   // [72,2260)
constexpr int TR0 = CVT0 + NB_CVT;             // 2260
constexpr int NB_T2BF = 808;                   // [2260,3068)
// gather+qw merged: 64 per-graph qw blocks FIRST, then 4096 data-gather
constexpr int NB_QW = 64;
constexpr int NB_GAD = 4096;
}

#define F4C(p) (*(const float4*)(p))

typedef __attribute__((ext_vector_type(8))) __bf16 bf16x8;
typedef __attribute__((ext_vector_type(4))) float floatx4;

__device__ __forceinline__ ushort f2bf(float f) {
  union { float f; unsigned u; } v;
  v.f = f;
  unsigned u = v.u;
  return (ushort)((u + 0x7fffu + ((u >> 16) & 1u)) >> 16);
}
__device__ __forceinline__ float bf2f(ushort u) {
  union { unsigned u; float f; } v;
  v.u = ((unsigned)u) << 16;
  return v.f;
}
__device__ __forceinline__ float4 us4f4(ushort4 u) {
  return make_float4(bf2f(u.x), bf2f(u.y), bf2f(u.z), bf2f(u.w));
}
__device__ __forceinline__ ushort4 f4us4(float4 f) {
  ushort4 o;
  o.x = f2bf(f.x); o.y = f2bf(f.y); o.z = f2bf(f.z); o.w = f2bf(f.w);
  return o;
}
__device__ __forceinline__ float fexp2(float x) {
#if __has_builtin(__builtin_amdgcn_exp2f)
  return __builtin_amdgcn_exp2f(x);
#else
  return exp2f(x);
#endif
}
__device__ __forceinline__ float frcp(float x) {
#if __has_builtin(__builtin_amdgcn_rcpf)
  return __builtin_amdgcn_rcpf(x);
#else
  return 1.0f / x;
#endif
}
__device__ __forceinline__ float fsigmoid(float z) {
  return frcp(1.0f + fexp2(z * -1.4426950408889634f));
}
__device__ __forceinline__ float fexp(float x) { return fexp2(x * 1.4426950408889634f); }

// XCD-affinity swizzle (low 6 bits only)
__device__ __forceinline__ int swz_g(int j) { return (((j >> 3) & 7) << 3) | (j & 7); }

// ---------------------------------------------------------------------------
// D1: per-graph CSR build (blocks FIRST) + conversions + weight transposes.
// grid 3068 x 256.  [verified R4-R10]
// ---------------------------------------------------------------------------
__global__ __launch_bounds__(256) void k_front_csr(
    const float* __restrict__ xd, const float* __restrict__ xq,
    const float* __restrict__ v0, const float* __restrict__ v1,
    const float* __restrict__ v2, ushort* __restrict__ oxd, ushort* __restrict__ oxq,
    ushort* __restrict__ ov0, ushort* __restrict__ ov1, ushort* __restrict__ ov2,
    const float* __restrict__ W1, const float* __restrict__ W2,
    const float* __restrict__ W3, const float* __restrict__ Wn0,
    const float* __restrict__ Wn1, const float* __restrict__ Wn2,
    ushort* __restrict__ o1, ushort* __restrict__ o2, ushort* __restrict__ o3,
    ushort* __restrict__ on0, ushort* __restrict__ on1, ushort* __restrict__ on2,
    const int* __restrict__ src_d, const int* __restrict__ dst_d,
    const int* __restrict__ src_q, const int* __restrict__ dst_q,
    int* __restrict__ cnt_d, int* __restrict__ cnt_q,
    int* __restrict__ rp_d, int* __restrict__ rp_q,
    float* __restrict__ dinv_d, float* __restrict__ dinv_q,
    int* __restrict__ col_d, int* __restrict__ col_q) {
  __shared__ float tile[32][33];
  __shared__ int s_cnt[512];
  __shared__ int s_base[512];
  __shared__ int s_cur[512];
  int blk = blockIdx.x, tid = threadIdx.x;
  if (blk < NB_CSRD) {
    int g = blk;
    const int* dstg = dst_d + g * 4096;
    const int* srcg = src_d + g * 4096;
    int nbase = g * 512;
    s_cnt[tid] = 0; s_cnt[tid + 256] = 0;
    __syncthreads();
    for (int e = tid; e < 4096; e += 256) atomicAdd(&s_cnt[dstg[e] - nbase], 1);
    __syncthreads();
    int c0 = s_cnt[tid], c1 = s_cnt[tid + 256];
    s_base[tid] = c0; s_base[tid + 256] = c1;
    __syncthreads();
    for (int off = 1; off < 512; off <<= 1) {
      int a = (tid >= off) ? s_base[tid - off] : 0;
      int b = (tid + 256 >= off) ? s_base[tid + 256 - off] : 0;
      __syncthreads();
      s_base[tid] += a; s_base[tid + 256] += b;
      __syncthreads();
    }
    int e0 = s_base[tid] - c0, e1 = s_base[tid + 256] - c1;
    s_base[tid] = e0; s_base[tid + 256] = e1;
    s_cur[tid] = 0; s_cur[tid + 256] = 0;
    cnt_d[nbase + tid] = c0;
    cnt_d[nbase + tid + 256] = c1;
    rp_d[nbase + tid] = g * 4096 + e0;
    rp_d[nbase + tid + 256] = g * 4096 + e1;
    dinv_d[nbase + tid] = 1.0f / sqrtf((float)(c0 + 1));
    dinv_d[nbase + tid + 256] = 1.0f / sqrtf((float)(c1 + 1));
    __syncthreads();
    for (int e = tid; e < 4096; e += 256) {
      int d = dstg[e] - nbase;
      int p = atomicAdd(&s_cur[d], 1);
      col_d[g * 4096 + s_base[d] + p] = srcg[e];
    }
  } else if (blk < CVT0) {
    int qb = blk - NB_CSRD;
    int lg = tid >> 5, lane32 = tid & 31;
    int g = qb * 8 + lg;
    const int* dstg = dst_q + g * 256;
    const int* srcg = src_q + g * 256;
    int nbase = g * 32;
    s_cnt[tid] = 0;
    __syncthreads();
#pragma unroll
    for (int j = 0; j < 8; ++j)
      atomicAdd(&s_cnt[lg * 32 + (dstg[lane32 + j * 32] - nbase)], 1);
    __syncthreads();
    int v = s_cnt[tid];
    int incl = v;
#pragma unroll
    for (int off = 1; off < 32; off <<= 1) {
      int t = __shfl_up(incl, off, 32);
      if (lane32 >= off) incl += t;
    }
    int excl = incl - v;
    cnt_q[nbase + lane32] = v;
    rp_q[nbase + lane32] = g * 256 + excl;
    dinv_q[nbase + lane32] = 1.0f / sqrtf((float)(v + 1));
    s_base[tid] = excl;
    s_cur[tid] = 0;
    __syncthreads();
#pragma unroll
    for (int j = 0; j < 8; ++j) {
      int e = lane32 + j * 32;
      int d = dstg[e] - nbase;
      int p = atomicAdd(&s_cur[lg * 32 + d], 1);
      col_q[g * 256 + s_base[lg * 32 + d] + p] = srcg[e];
    }
  } else if (blk < TR0) {
    int b2 = blk - CVT0;
    const float* src;
    ushort* dst;
    int i;
    if (b2 < 2048) { src = xd; dst = oxd; i = b2 * 256 + tid; }
    else if (b2 < 2176) { src = xq; dst = oxq; i = (b2 - 2048) * 256 + tid; }
    else if (b2 < 2180) { src = v0; dst = ov0; i = (b2 - 2176) * 256 + tid; }
    else if (b2 < 2184) { src = v1; dst = ov1; i = (b2 - 2180) * 256 + tid; }
    else { src = v2; dst = ov2; i = (b2 - 2184) * 256 + tid; }
    *(ushort4*)(dst + (size_t)i * 4) = f4us4(F4C(src + (size_t)i * 4));
  } else {
    int b5 = blk - TR0;
    const float* in;
    ushort* out;
    int R, C, bt, t;
    if (b5 < 8)        { in = W1;  out = o1;  R = 64;  C = 128; bt = 0; t = b5; }
    else if (b5 < 24)  { in = W2;  out = o2;  R = 128; C = 128; bt = 0; t = b5 - 8; }
    else if (b5 < 40)  { in = W3;  out = o3;  R = 128; C = 128; bt = 0; t = b5 - 24; }
    else if (b5 < 296) { in = Wn0; out = on0; R = 128; C = 128; bt = (b5 - 40) >> 4;  t = (b5 - 40) & 15; }
    else if (b5 < 552) { in = Wn1; out = on1; R = 128; C = 128; bt = (b5 - 296) >> 4; t = (b5 - 296) & 15; }
    else               { in = Wn2; out = on2; R = 128; C = 128; bt = (b5 - 552) >> 4; t = (b5 - 552) & 15; }
    int tilesC = C >> 5;
    int tr = t / tilesC, tc = t - tr * tilesC;
    int tx = tid & 31, ty = tid >> 5;
    const float* ib = in + (size_t)bt * R * C;
    ushort* ob = out + (size_t)bt * R * C;
#pragma unroll
    for (int i = 0; i < 4; ++i)
      tile[ty + i * 8][tx] = ib[(tr * 32 + ty + i * 8) * C + tc * 32 + tx];
    __syncthreads();
#pragma unroll
    for (int i = 0; i < 4; ++i)
      ob[(size_t)(tc * 32 + ty + i * 8) * R + tr * 32 + tx] = f2bf(tile[tx][ty + i * 8]);
  }
}

// ---------------------------------------------------------------------------
// D2: GCN GEMM layer 1 (KD=64). grid 544 x 256. [verified]
// ---------------------------------------------------------------------------
__global__ __launch_bounds__(256) void k_gemm1(
    const ushort* __restrict__ xdbf, const ushort* __restrict__ xqbf,
    const ushort* __restrict__ w1T, const float* __restrict__ dinv_d,
    const float* __restrict__ dinv_q, ushort* __restrict__ htmp) {
  int blk2 = blockIdx.x, tid = threadIdx.x;
  int wave = tid >> 6, lane = tid & 63;
  int col = lane & 15, quad = lane >> 4;
  bool isQ = blk2 >= 512;
  int node0;
  if (isQ) node0 = (blk2 - 512) * 64;
  else node0 = swz_g(blk2) * 512 + (blk2 >> 6) * 64;
  int mloc = node0 + wave * 16;
  const ushort* X = isQ ? xqbf : xdbf;
  const float* dv = isQ ? dinv_q : dinv_d;
  size_t hbase = isQ ? (size_t)cNd : 0;
  floatx4 acc[8];
#pragma unroll
  for (int ct = 0; ct < 8; ++ct)
#pragma unroll
    for (int r = 0; r < 4; ++r) acc[ct][r] = 0.0f;
#pragma unroll
  for (int kc = 0; kc < 2; ++kc) {
    bf16x8 a = *(const bf16x8*)(X + (size_t)(mloc + col) * 64 + kc * 32 + quad * 8);
#pragma unroll
    for (int ct = 0; ct < 8; ++ct) {
      bf16x8 b = *(const bf16x8*)(w1T + (size_t)(ct * 16 + col) * 64 + kc * 32 + quad * 8);
      acc[ct] = __builtin_amdgcn_mfma_f32_16x16x32_bf16(a, b, acc[ct], 0, 0, 0);
    }
  }
  float sc[4];
#pragma unroll
  for (int r = 0; r < 4; ++r) sc[r] = dv[mloc + quad * 4 + r];
#pragma unroll
  for (int ct = 0; ct < 8; ++ct)
#pragma unroll
    for (int r = 0; r < 4; ++r)
      htmp[(hbase + mloc + quad * 4 + r) * 128 + ct * 16 + col] = f2bf(acc[ct][r] * sc[r]);
}

// ---------------------------------------------------------------------------
// Merged: per-graph {query-gather + qbf + qW all 16 k} [blk<64, FIRST] +
// data gather [blk in [64, 64+4096), R0-verified]. The 64 qw blocks gather
// their graph's 32 q-rows ONCE (R9-verified numerics), write qbf, stage rows
// in XOR-swizzled LDS, then loop k=0..15 running the exact gmn_qw MFMA body.
// No redundancy (was 16x in R9), no tail (was the R9 critical-path bug).
// ---------------------------------------------------------------------------
__global__ __launch_bounds__(256) void k_gather_qw(
    const ushort* __restrict__ htmp, const int* __restrict__ rp_d,
    const int* __restrict__ cnt_d, const int* __restrict__ col_d,
    const float* __restrict__ dinv_d, const int* __restrict__ rp_q,
    const int* __restrict__ cnt_q, const int* __restrict__ col_q,
    const float* __restrict__ dinv_q, const float* __restrict__ bias,
    ushort* __restrict__ dbf, ushort* __restrict__ qbf,
    const ushort* __restrict__ wnT, ushort* __restrict__ qw) {
  __shared__ ushort q_s[32 * 128];  // 8 KB, XOR-swizzled bf16 q rows
  int blk = blockIdx.x, tid = threadIdx.x;
  if (blk >= NB_QW) {
    // ---------------- data gather (R0-verified logic) ----------------------
    int j = blk - NB_QW;
    int node = swz_g(j) * 512 + (j >> 6) * 8 + (tid >> 5);
    int l = tid & 31;
    int c = cnt_d[node], s0 = rp_d[node];
    float dt = dinv_d[node];
    float4 acc = us4f4(*(const ushort4*)(htmp + (size_t)node * 128 + l * 4));
    int cm = c < 32 ? c : 32;
    for (int j0 = 0; j0 < cm; j0 += 8) {
      int ss[8];
      ushort4 v[8];
#pragma unroll
      for (int t = 0; t < 8; ++t) {
        int jj = j0 + t;
        ss[t] = (jj < cm) ? col_d[s0 + jj] : -1;
      }
#pragma unroll
      for (int t = 0; t < 8; ++t)
        if (ss[t] >= 0) v[t] = *(const ushort4*)(htmp + (size_t)ss[t] * 128 + l * 4);
#pragma unroll
      for (int t = 0; t < 8; ++t) {
        if (ss[t] >= 0) {
          float4 f = us4f4(v[t]);
          acc.x += f.x; acc.y += f.y; acc.z += f.z; acc.w += f.w;
        }
      }
    }
    for (int j2 = 32; j2 < c; ++j2) {
      int s = col_d[s0 + j2];
      float4 f = us4f4(*(const ushort4*)(htmp + (size_t)s * 128 + l * 4));
      acc.x += f.x; acc.y += f.y; acc.z += f.z; acc.w += f.w;
    }
    float4 bv = F4C(bias + l * 4);
    float4 r;
    r.x = fmaxf(acc.x * dt + bv.x, 0.0f);
    r.y = fmaxf(acc.y * dt + bv.y, 0.0f);
    r.z = fmaxf(acc.z * dt + bv.z, 0.0f);
    r.w = fmaxf(acc.w * dt + bv.w, 0.0f);
    *(ushort4*)(dbf + (size_t)node * 128 + l * 4) = f4us4(r);
    return;
  }
  // ---------------- per-graph query gather + qbf + qW ----------------------
  int b = swz_g(blk);
  {
    // gather graph b's 32 query rows (R9-verified numerics; same reduce order
    // as the R0 gather: own row first, then CSR neighbors ascending)
    int n = tid >> 3, seg = tid & 7, d0 = seg * 16;
    int node = b * 32 + n;
    int c = cnt_q[node], s0 = rp_q[node];
    float dt = dinv_q[node];
    const ushort* hq = htmp + (size_t)cNd * 128;
    const ushort* own = hq + (size_t)node * 128 + d0;
    float4 a0 = us4f4(*(const ushort4*)(own));
    float4 a1 = us4f4(*(const ushort4*)(own + 4));
    float4 a2 = us4f4(*(const ushort4*)(own + 8));
    float4 a3 = us4f4(*(const ushort4*)(own + 12));
    for (int j2 = 0; j2 < c; ++j2) {
      int s = col_q[s0 + j2];
      const ushort* rr = hq + (size_t)s * 128 + d0;
      float4 f0 = us4f4(*(const ushort4*)(rr));
      float4 f1 = us4f4(*(const ushort4*)(rr + 4));
      float4 f2 = us4f4(*(const ushort4*)(rr + 8));
      float4 f3 = us4f4(*(const ushort4*)(rr + 12));
      a0.x += f0.x; a0.y += f0.y; a0.z += f0.z; a0.w += f0.w;
      a1.x += f1.x; a1.y += f1.y; a1.z += f1.z; a1.w += f1.w;
      a2.x += f2.x; a2.y += f2.y; a2.z += f2.z; a2.w += f2.w;
      a3.x += f3.x; a3.y += f3.y; a3.z += f3.z; a3.w += f3.w;
    }
    float4 bv0 = F4C(bias + d0), bv1 = F4C(bias + d0 + 4);
    float4 bv2 = F4C(bias + d0 + 8), bv3 = F4C(bias + d0 + 12);
    float4 r0, r1, r2, r3;
    r0.x = fmaxf(a0.x * dt + bv0.x, 0.0f); r0.y = fmaxf(a0.y * dt + bv0.y, 0.0f);
    r0.z = fmaxf(a0.z * dt + bv0.z, 0.0f); r0.w = fmaxf(a0.w * dt + bv0.w, 0.0f);
    r1.x = fmaxf(a1.x * dt + bv1.x, 0.0f); r1.y = fmaxf(a1.y * dt + bv1.y, 0.0f);
    r1.z = fmaxf(a1.z * dt + bv1.z, 0.0f); r1.w = fmaxf(a1.w * dt + bv1.w, 0.0f);
    r2.x = fmaxf(a2.x * dt + bv2.x, 0.0f); r2.y = fmaxf(a2.y * dt + bv2.y, 0.0f);
    r2.z = fmaxf(a2.z * dt + bv2.z, 0.0f); r2.w = fmaxf(a2.w * dt + bv2.w, 0.0f);
    r3.x = fmaxf(a3.x * dt + bv3.x, 0.0f); r3.y = fmaxf(a3.y * dt + bv3.y, 0.0f);
    r3.z = fmaxf(a3.z * dt + bv3.z, 0.0f); r3.w = fmaxf(a3.w * dt + bv3.w, 0.0f);
    ushort4 u0 = f4us4(r0), u1 = f4us4(r1), u2 = f4us4(r2), u3 = f4us4(r3);
    // qbf global write (replaces the old query-gather blocks; same values)
    *(ushort4*)(qbf + (size_t)node * 128 + d0) = u0;
    *(ushort4*)(qbf + (size_t)node * 128 + d0 + 4) = u1;
    *(ushort4*)(qbf + (size_t)node * 128 + d0 + 8) = u2;
    *(ushort4*)(qbf + (size_t)node * 128 + d0 + 12) = u3;
    // LDS swizzled store: 16B chunks XOR'd by (row&7)<<4 (R9-verified layout)
    char* qsb = (char*)q_s;
    int x0 = (n * 256 + d0 * 2) ^ ((n & 7) << 4);
    int x1 = (n * 256 + d0 * 2 + 16) ^ ((n & 7) << 4);
    *(ushort4*)(qsb + x0) = u0;
    *(ushort4*)(qsb + x0 + 8) = u1;
    *(ushort4*)(qsb + x1) = u2;
    *(ushort4*)(qsb + x1 + 8) = u3;
  }
  __syncthreads();
  // qW for ALL 16 k of this graph (exact gmn_qw MFMA body + output layout);
  // a-fragments are k-invariant -> hoisted out of the k loop.
  int wave = tid >> 6, lane = tid & 63;
  int col = lane & 15, quad = lane >> 4;
  int et0 = wave * 2;
  const char* qsb = (const char*)q_s;
  bf16x8 qa0[4], qa1[4];
#pragma unroll
  for (int kc = 0; kc < 4; ++kc) {
    int r0 = col, r1 = 16 + col;
    qa0[kc] = *(const bf16x8*)(qsb + ((r0 * 256 + kc * 64 + quad * 16) ^ ((r0 & 7) << 4)));
    qa1[kc] = *(const bf16x8*)(qsb + ((r1 * 256 + kc * 64 + quad * 16) ^ ((r1 & 7) << 4)));
  }
  for (int k = 0; k < 16; ++k) {
    floatx4 acc[2][2];
#pragma unroll
    for (int qt = 0; qt < 2; ++qt)
#pragma unroll
      for (int ei = 0; ei < 2; ++ei)
#pragma unroll
        for (int r = 0; r < 4; ++r) acc[qt][ei][r] = 0.0f;
#pragma unroll
    for (int kc = 0; kc < 4; ++kc) {
#pragma unroll
      for (int ei = 0; ei < 2; ++ei) {
        bf16x8 bf = *(const bf16x8*)(wnT + (size_t)(k * 128 + (et0 + ei) * 16 + col) * 128 +
                                     kc * 32 + quad * 8);
        acc[0][ei] = __builtin_amdgcn_mfma_f32_16x16x32_bf16(qa0[kc], bf, acc[0][ei], 0, 0, 0);
        acc[1][ei] = __builtin_amdgcn_mfma_f32_16x16x32_bf16(qa1[kc], bf, acc[1][ei], 0, 0, 0);
      }
    }
#pragma unroll
    for (int qt = 0; qt < 2; ++qt)
#pragma unroll
      for (int ei = 0; ei < 2; ++ei)
#pragma unroll
        for (int r = 0; r < 4; ++r)
          qw[((size_t)(b * 16 + k) << 12) + (qt * 16 + quad * 4 + r) * 128 +
             (et0 + ei) * 16 + col] = f2bf(acc[qt][ei][r]);
  }
}

// ---------------------------------------------------------------------------
// Merged dispatch (byte-identical to R8's verified k_level_gemm): fused NTN
// level reading qw from GLOBAL (no k-loop barriers, 4-s ILP) [blk<128] +
// next-layer GCN GEMM KD=128 [blk in [128,400)]. __launch_bounds__(512,2).
// ---------------------------------------------------------------------------
__global__ __launch_bounds__(512, 2) void k_level_gemm(
    const ushort* __restrict__ qbf, const ushort* __restrict__ dbf,
    const ushort* __restrict__ qw, const ushort* __restrict__ vnbf,
    const float* __restrict__ bn, const float* __restrict__ cw,
    const float* __restrict__ w_end, const float* __restrict__ b_end,
    int o1, int o2, int hasF, int do_sm, int mode, int widx,
    float* __restrict__ accb, float* __restrict__ out,
    const ushort* __restrict__ gWT, const float* __restrict__ dinv_d,
    const float* __restrict__ dinv_q, ushort* __restrict__ htmp) {
  __shared__ float s_ld[16 * LD_STRIDE];
  __shared__ float s_lq[16 * 16];
  __shared__ float s_red[16 * 8];
  int tid = threadIdx.x;
  int wave = tid >> 6, lane = tid & 63;
  int col = lane & 15, quad = lane >> 4;

  if (blockIdx.x >= 128) {  // ---------------- GEMM KD=128 section ----------
    int gblk = blockIdx.x - 128;  // [0,272): data [0,256), query [256,272)
    bool isQ = gblk >= 256;
    int node0;
    if (isQ) node0 = (gblk - 256) * 128;
    else node0 = swz_g(gblk) * 512 + (gblk >> 6) * 128;
    int mloc = node0 + wave * 16;
    const ushort* X = isQ ? qbf : dbf;
    const float* dv = isQ ? dinv_q : dinv_d;
    size_t hbase = isQ ? (size_t)cNd : 0;
    floatx4 acc[8];
#pragma unroll
    for (int ct = 0; ct < 8; ++ct)
#pragma unroll
      for (int r = 0; r < 4; ++r) acc[ct][r] = 0.0f;
#pragma unroll
    for (int kc = 0; kc < 4; ++kc) {
      bf16x8 a = *(const bf16x8*)(X + (size_t)(mloc + col) * 128 + kc * 32 + quad * 8);
#pragma unroll
      for (int ct = 0; ct < 8; ++ct) {
        bf16x8 b = *(const bf16x8*)(gWT + (size_t)(ct * 16 + col) * 128 + kc * 32 + quad * 8);
        acc[ct] = __builtin_amdgcn_mfma_f32_16x16x32_bf16(a, b, acc[ct], 0, 0, 0);
      }
    }
    float sc[4];
#pragma unroll
    for (int r = 0; r < 4; ++r) sc[r] = dv[mloc + quad * 4 + r];
#pragma unroll
    for (int ct = 0; ct < 8; ++ct)
#pragma unroll
      for (int r = 0; r < 4; ++r)
        htmp[(hbase + mloc + quad * 4 + r) * 128 + ct * 16 + col] = f2bf(acc[ct][r] * sc[r]);
    return;
  }

  // ---------------- fused level section ------------------------------------
  int b = swz_g(blockIdx.x & 63);
  int qh = blockIdx.x >> 6;
  int n0 = wave * 64;

  bf16x8 bfr[4][4];
#pragma unroll
  for (int s = 0; s < 4; ++s)
#pragma unroll
    for (int kc = 0; kc < 4; ++kc)
      bfr[s][kc] = *(const bf16x8*)(dbf + ((size_t)(b * 512 + n0 + s * 16 + col) << 7) +
                                    kc * 32 + quad * 8);
  bf16x8 aq[4];
#pragma unroll
  for (int kc = 0; kc < 4; ++kc)
    aq[kc] = *(const bf16x8*)(qbf + (size_t)(b * 32 + qh * 16 + col) * 128 +
                              kc * 32 + quad * 8);

  floatx4 att[4];
#pragma unroll
  for (int s = 0; s < 4; ++s)
#pragma unroll
    for (int r = 0; r < 4; ++r) att[s][r] = 0.0f;
#pragma unroll
  for (int kc = 0; kc < 4; ++kc)
#pragma unroll
    for (int s = 0; s < 4; ++s)
      att[s] = __builtin_amdgcn_mfma_f32_16x16x32_bf16(aq[kc], bfr[s][kc], att[s], 0, 0, 0);
  const float sc = 0.088388347648318440550f;
#pragma unroll
  for (int s = 0; s < 4; ++s)
#pragma unroll
    for (int r = 0; r < 4; ++r) att[s][r] *= sc;

  {
    bf16x8 vn2[4];
#pragma unroll
    for (int kc = 0; kc < 4; ++kc)
      vn2[kc] = *(const bf16x8*)(vnbf + col * 256 + 128 + kc * 32 + quad * 8);
#pragma unroll
    for (int s = 0; s < 4; ++s) {
      floatx4 lda;
#pragma unroll
      for (int r = 0; r < 4; ++r) lda[r] = 0.0f;
#pragma unroll
      for (int kc = 0; kc < 4; ++kc)
        lda = __builtin_amdgcn_mfma_f32_16x16x32_bf16(bfr[s][kc], vn2[kc], lda, 0, 0, 0);
#pragma unroll
      for (int r = 0; r < 4; ++r)
        s_ld[col * LD_STRIDE + n0 + s * 16 + quad * 4 + r] = lda[r];
    }
  }
  if (wave == 0) {
    bf16x8 vn1[4];
#pragma unroll
    for (int kc = 0; kc < 4; ++kc)
      vn1[kc] = *(const bf16x8*)(vnbf + col * 256 + kc * 32 + quad * 8);
    floatx4 lqa;
#pragma unroll
    for (int r = 0; r < 4; ++r) lqa[r] = 0.0f;
#pragma unroll
    for (int kc = 0; kc < 4; ++kc)
      lqa = __builtin_amdgcn_mfma_f32_16x16x32_bf16(aq[kc], vn1[kc], lqa, 0, 0, 0);
#pragma unroll
    for (int r = 0; r < 4; ++r) s_lq[col * 16 + quad * 4 + r] = lqa[r];
  }
  __syncthreads();

  float red[4], M[4];
#pragma unroll
  for (int r = 0; r < 4; ++r) {
    float m = fmaxf(fmaxf(att[0][r], att[1][r]), fmaxf(att[2][r], att[3][r]));
#pragma unroll
    for (int o = 1; o < 16; o <<= 1) m = fmaxf(m, __shfl_xor(m, o, 64));
    red[r] = m;
  }
  if (col == 0)
#pragma unroll
    for (int r = 0; r < 4; ++r) s_red[(quad * 4 + r) * 8 + wave] = red[r];
  __syncthreads();
#pragma unroll
  for (int r = 0; r < 4; ++r) {
    float m = s_red[(quad * 4 + r) * 8];
#pragma unroll
    for (int w = 1; w < 8; ++w) m = fmaxf(m, s_red[(quad * 4 + r) * 8 + w]);
    M[r] = m;
  }
  __syncthreads();
#pragma unroll
  for (int s = 0; s < 4; ++s)
#pragma unroll
    for (int r = 0; r < 4; ++r) att[s][r] = fexp(att[s][r] - M[r]);
#pragma unroll
  for (int r = 0; r < 4; ++r) {
    float m = att[0][r] + att[1][r] + att[2][r] + att[3][r];
#pragma unroll
    for (int o = 1; o < 16; o <<= 1) m += __shfl_xor(m, o, 64);
    red[r] = m;
  }
  if (col == 0)
#pragma unroll
    for (int r = 0; r < 4; ++r) s_red[(quad * 4 + r) * 8 + wave] = red[r];
  __syncthreads();
#pragma unroll
  for (int r = 0; r < 4; ++r) {
    float m = s_red[(quad * 4 + r) * 8];
#pragma unroll
    for (int w = 1; w < 8; ++w) m += s_red[(quad * 4 + r) * 8 + w];
    M[r] = frcp(m);
  }
  __syncthreads();
#pragma unroll
  for (int s = 0; s < 4; ++s)
#pragma unroll
    for (int r = 0; r < 4; ++r) att[s][r] *= M[r];

  floatx4 eacc[4], facc[4];
#pragma unroll
  for (int s = 0; s < 4; ++s)
#pragma unroll
    for (int r = 0; r < 4; ++r) { eacc[s][r] = 0.0f; facc[s][r] = 0.0f; }

#pragma unroll 4
  for (int k = 0; k < 16; ++k) {
    const ushort* qk = qw + ((size_t)(b * 16 + k) << 12) + (qh * 16 + col) * 128 + quad * 8;
    bf16x8 a0 = *(const bf16x8*)(qk);
    bf16x8 a1 = *(const bf16x8*)(qk + 32);
    bf16x8 a2 = *(const bf16x8*)(qk + 64);
    bf16x8 a3 = *(const bf16x8*)(qk + 96);
    floatx4 bil[4];
#pragma unroll
    for (int s = 0; s < 4; ++s) {
#pragma unroll
      for (int r = 0; r < 4; ++r) bil[s][r] = 0.0f;
      bil[s] = __builtin_amdgcn_mfma_f32_16x16x32_bf16(a0, bfr[s][0], bil[s], 0, 0, 0);
      bil[s] = __builtin_amdgcn_mfma_f32_16x16x32_bf16(a1, bfr[s][1], bil[s], 0, 0, 0);
      bil[s] = __builtin_amdgcn_mfma_f32_16x16x32_bf16(a2, bfr[s][2], bil[s], 0, 0, 0);
      bil[s] = __builtin_amdgcn_mfma_f32_16x16x32_bf16(a3, bfr[s][3], bil[s], 0, 0, 0);
    }
    float bnk = bn[k], cwk = cw[k];
    float wkk = 0.0f;
    if (hasF) {
      wkk = w_end[o1 + k];
      if (o2 >= 0) wkk += w_end[o2 + k];
    }
    float lqv[4];
#pragma unroll
    for (int r = 0; r < 4; ++r) lqv[r] = s_lq[k * 16 + quad * 4 + r] + bnk;
#pragma unroll
    for (int s = 0; s < 4; ++s) {
      float ldv = s_ld[k * LD_STRIDE + n0 + s * 16 + col];
#pragma unroll
      for (int r = 0; r < 4; ++r) {
        float sg = fsigmoid(bil[s][r] + lqv[r] + ldv);
        eacc[s][r] += cwk * sg;
        facc[s][r] += wkk * sg;
      }
    }
  }

#pragma unroll
  for (int s = 0; s < 4; ++s)
#pragma unroll
    for (int r = 0; r < 4; ++r) {
      eacc[s][r] *= att[s][r];
      facc[s][r] *= att[s][r];
    }
  if (do_sm) {
#pragma unroll
    for (int r = 0; r < 4; ++r) {
      float m = fmaxf(fmaxf(eacc[0][r], eacc[1][r]), fmaxf(eacc[2][r], eacc[3][r]));
#pragma unroll
      for (int o = 1; o < 16; o <<= 1) m = fmaxf(m, __shfl_xor(m, o, 64));
      red[r] = m;
    }
    if (col == 0)
#pragma unroll
      for (int r = 0; r < 4; ++r) s_red[(quad * 4 + r) * 8 + wave] = red[r];
    __syncthreads();
#pragma unroll
    for (int r = 0; r < 4; ++r) {
      float m = s_red[(quad * 4 + r) * 8];
#pragma unroll
      for (int w = 1; w < 8; ++w) m = fmaxf(m, s_red[(quad * 4 + r) * 8 + w]);
      M[r] = m;
    }
    __syncthreads();
#pragma unroll
    for (int s = 0; s < 4; ++s)
#pragma unroll
      for (int r = 0; r < 4; ++r) eacc[s][r] = fexp(eacc[s][r] - M[r]);
#pragma unroll
    for (int r = 0; r < 4; ++r) {
      float m = eacc[0][r] + eacc[1][r] + eacc[2][r] + eacc[3][r];
#pragma unroll
      for (int o = 1; o < 16; o <<= 1) m += __shfl_xor(m, o, 64);
      red[r] = m;
    }
    if (col == 0)
#pragma unroll
      for (int r = 0; r < 4; ++r) s_red[(quad * 4 + r) * 8 + wave] = red[r];
    __syncthreads();
#pragma unroll
    for (int r = 0; r < 4; ++r) {
      float m = s_red[(quad * 4 + r) * 8];
#pragma unroll
      for (int w = 1; w < 8; ++w) m += s_red[(quad * 4 + r) * 8 + w];
      M[r] = frcp(m);
    }
    __syncthreads();
#pragma unroll
    for (int s = 0; s < 4; ++s)
#pragma unroll
      for (int r = 0; r < 4; ++r) eacc[s][r] *= M[r];
  }
  float w = w_end[widx];
#pragma unroll
  for (int s = 0; s < 4; ++s)
#pragma unroll
    for (int r = 0; r < 4; ++r) eacc[s][r] = w * eacc[s][r] + (hasF ? facc[s][r] : 0.0f);

  if (mode == 0) {
#pragma unroll
    for (int s = 0; s < 4; ++s)
#pragma unroll
      for (int r = 0; r < 4; ++r)
        accb[((size_t)(b * 32 + qh * 16 + quad * 4 + r) << 9) + n0 + s * 16 + col] =
            eacc[s][r];
  } else if (mode == 1) {
#pragma unroll
    for (int s = 0; s < 4; ++s)
#pragma unroll
      for (int r = 0; r < 4; ++r)
        accb[((size_t)(b * 32 + qh * 16 + quad * 4 + r) << 9) + n0 + s * 16 + col] +=
            eacc[s][r];
  } else {
    float be = b_end[0];
#pragma unroll
    for (int s = 0; s < 4; ++s)
#pragma unroll
      for (int r = 0; r < 4; ++r)
        eacc[s][r] += accb[((size_t)(b * 32 + qh * 16 + quad * 4 + r) << 9) +
                           n0 + s * 16 + col] + be;
#pragma unroll
    for (int r = 0; r < 4; ++r) {
      float m = fmaxf(fmaxf(eacc[0][r], eacc[1][r]), fmaxf(eacc[2][r], eacc[3][r]));
#pragma unroll
      for (int o = 1; o < 16; o <<= 1) m = fmaxf(m, __shfl_xor(m, o, 64));
      red[r] = m;
    }
    if (col == 0)
#pragma unroll
      for (int r = 0; r < 4; ++r) s_red[(quad * 4 + r) * 8 + wave] = red[r];
    __syncthreads();
#pragma unroll
    for (int r = 0; r < 4; ++r) {
      float m = s_red[(quad * 4 + r) * 8];
#pragma unroll
      for (int w2 = 1; w2 < 8; ++w2) m = fmaxf(m, s_red[(quad * 4 + r) * 8 + w2]);
      M[r] = m;
    }
    __syncthreads();
#pragma unroll
    for (int s = 0; s < 4; ++s)
#pragma unroll
      for (int r = 0; r < 4; ++r) eacc[s][r] = fexp(eacc[s][r] - M[r]);
#pragma unroll
    for (int r = 0; r < 4; ++r) {
      float m = eacc[0][r] + eacc[1][r] + eacc[2][r] + eacc[3][r];
#pragma unroll
      for (int o = 1; o < 16; o <<= 1) m += __shfl_xor(m, o, 64);
      red[r] = m;
    }
    if (col == 0)
#pragma unroll
      for (int r = 0; r < 4; ++r) s_red[(quad * 4 + r) * 8 + wave] = red[r];
    __syncthreads();
#pragma unroll
    for (int r = 0; r < 4; ++r) {
      float m = s_red[(quad * 4 + r) * 8];
#pragma unroll
      for (int w2 = 1; w2 < 8; ++w2) m += s_red[(quad * 4 + r) * 8 + w2];
      M[r] = frcp(m);
    }
#pragma unroll
    for (int s = 0; s < 4; ++s)
#pragma unroll
      for (int r = 0; r < 4; ++r)
        out[((size_t)(b * 32 + qh * 16 + quad * 4 + r) << 9) + n0 + s * 16 + col] =
            eacc[s][r] * M[r];
  }
}

// ---------------------------------------------------------------------------
// Host orchestration — 8 dispatches:
// front_csr, gemm1, [gather+qw(per-graph, head-of-grid), level(+gemm)] x3
// ---------------------------------------------------------------------------
extern "C" void kernel_launch(void* const* d_in, const int* in_sizes, int n_in,
                              void* d_out, int out_size, void* d_ws, size_t ws_size,
                              hipStream_t stream) {
  (void)in_sizes; (void)n_in; (void)out_size; (void)ws_size;
  const float* x_d = (const float*)d_in[0];
  const float* x_q = (const float*)d_in[1];
  const int* ei_d = (const int*)d_in[2];
  const int* ei_q = (const int*)d_in[3];
  const float* W1 = (const float*)d_in[6];
  const float* b1 = (const float*)d_in[7];
  const float* W2 = (const float*)d_in[8];
  const float* b2 = (const float*)d_in[9];
  const float* W3 = (const float*)d_in[10];
  const float* b3 = (const float*)d_in[11];
  const float* Wn[3] = {(const float*)d_in[12], (const float*)d_in[17], (const float*)d_in[22]};
  const float* Vn[3] = {(const float*)d_in[13], (const float*)d_in[18], (const float*)d_in[23]};
  const float* bn[3] = {(const float*)d_in[14], (const float*)d_in[19], (const float*)d_in[24]};
  const float* cw[3] = {(const float*)d_in[15], (const float*)d_in[20], (const float*)d_in[25]};
  const float* w_end = (const float*)d_in[27];
  const float* b_end = (const float*)d_in[28];
  float* out = (float*)d_out;

  char* wsp = (char*)d_ws;
  auto alloc = [&](size_t nbytes) {
    void* p = (void*)wsp;
    wsp += (nbytes + 255) & ~(size_t)255;
    return p;
  };
  int* cnt_d = (int*)alloc(cNd * 4);
  int* cnt_q = (int*)alloc(cNq * 4);
  float* dinv_d = (float*)alloc(cNd * 4);
  float* dinv_q = (float*)alloc(cNq * 4);
  int* rp_d = (int*)alloc(cNd * 4);
  int* rp_q = (int*)alloc(cNq * 4);
  int* col_d = (int*)alloc((size_t)cEd * 4);
  int* col_q = (int*)alloc((size_t)cEq * 4);
  ushort* xdbf = (ushort*)alloc((size_t)cNd * 64 * 2);
  ushort* xqbf = (ushort*)alloc((size_t)cNq * 64 * 2);
  ushort* w1T = (ushort*)alloc(128 * 64 * 2);
  ushort* w2T = (ushort*)alloc(128 * 128 * 2);
  ushort* w3T = (ushort*)alloc(128 * 128 * 2);
  ushort* wnT[3];
  for (int l = 0; l < 3; ++l) wnT[l] = (ushort*)alloc((size_t)16 * 128 * 128 * 2);
  ushort* vnbf[3];
  for (int l = 0; l < 3; ++l) vnbf[l] = (ushort*)alloc(16 * 256 * 2);
  ushort* htmp = (ushort*)alloc((size_t)(cNd + cNq) * 128 * 2);
  ushort* dbf = (ushort*)alloc((size_t)cNd * 128 * 2);
  ushort* qbf[3];
  for (int l = 0; l < 3; ++l) qbf[l] = (ushort*)alloc((size_t)cNq * 128 * 2);
  float* accb = (float*)alloc((size_t)cB * cNQ * cND * 4);
  ushort* qwbuf = (ushort*)alloc((size_t)cB * 16 * 32 * 128 * 2);

  const int* src_d = ei_d;
  const int* dst_d = ei_d + cEd;
  const int* src_q = ei_q;
  const int* dst_q = ei_q + cEq;

  // D1: CSR build (first blocks) + conversions + transposes (no memset needed)
  k_front_csr<<<TR0 + NB_T2BF, 256, 0, stream>>>(
      x_d, x_q, Vn[0], Vn[1], Vn[2], xdbf, xqbf, vnbf[0], vnbf[1], vnbf[2], W1, W2,
      W3, Wn[0], Wn[1], Wn[2], w1T, w2T, w3T, wnT[0], wnT[1], wnT[2],
      src_d, dst_d, src_q, dst_q, cnt_d, cnt_q, rp_d, rp_q, dinv_d, dinv_q,
      col_d, col_q);

  // D2: GEMM layer 1
  k_gemm1<<<544, 256, 0, stream>>>(xdbf, xqbf, w1T, dinv_d, dinv_q, htmp);

  const float* bias[3] = {b1, b2, b3};
  const ushort* nextWT[3] = {w2T, w3T, nullptr};
  const int o1s[3] = {0, 19, 3};
  const int o2s[3] = {-1, -1, 35};
  const int hasF[3] = {0, 1, 1};
  const int dosms[3] = {1, 0, 1};
  const int modes[3] = {0, 1, 2};

  for (int l = 0; l < 3; ++l) {
    // gather layer l -> dbf  AND  per-graph {q-gather -> qbf[l], qW -> qwbuf}
    // (qw blocks FIRST: no tail, no redundancy; both sections read only htmp)
    k_gather_qw<<<NB_QW + NB_GAD, 256, 0, stream>>>(
        htmp, rp_d, cnt_d, col_d, dinv_d, rp_q, cnt_q, col_q, dinv_q, bias[l], dbf,
        qbf[l], wnT[l], qwbuf);
    // fused level l (global qw reads, barrier-free k-loop) + GEMM for layer l+1
    int grid = (l < 2) ? (128 + 272) : 128;
    k_level_gemm<<<grid, 512, 0, stream>>>(
        qbf[l], dbf, qwbuf, vnbf[l], bn[l], cw[l], w_end, b_end, o1s[l], o2s[l],
        hasF[l], dosms[l], modes[l], l, accb, out, nextWT[l], dinv_d, dinv_q, htmp);
  }
}

// Round 12
// 292.999 us; speedup vs baseline: 1.1060x; 1.1060x over previous
//
#include <hip/hip_runtime.h>
#include <math.h>

// ---------------------------------------------------------------------------
// Problem constants (fixed production sizes from the reference)
// ---------------------------------------------------------------------------
namespace {
constexpr int cB  = 64;
constexpr int cNQ = 32;
constexpr int cND = 512;
constexpr int cNd = cB * cND;   // 32768
constexpr int cNq = cB * cNQ;   // 2048
constexpr int cEd = cNd * 8;    // 262144 (exactly 4096 per graph, graph-sorted)
constexpr int cEq = cNq * 8;    // 16384  (exactly 256 per graph, graph-sorted)
constexpr int LD_STRIDE = 516;
// front kernel block ranges: CSR first (starts immediately), then cvt/transpose
constexpr int NB_CSRD = 64;                    // [0,64)
constexpr int NB_CSRQ = 8;                     // [64,72)
constexpr int CVT0 = NB_CSRD + NB_CSRQ;        // 72
constexpr int NB_CVT = 2188;                   // [72,2260)
constexpr int TR0 = CVT0 + NB_CVT;             // 2260
constexpr int NB_T2BF = 808;                   // [2260,3068)
}

#define F4C(p) (*(const float4*)(p))

typedef __attribute__((ext_vector_type(8))) __bf16 bf16x8;
typedef __attribute__((ext_vector_type(4))) float floatx4;

__device__ __forceinline__ ushort f2bf(float f) {
  union { float f; unsigned u; } v;
  v.f = f;
  unsigned u = v.u;
  return (ushort)((u + 0x7fffu + ((u >> 16) & 1u)) >> 16);
}
__device__ __forceinline__ float bf2f(ushort u) {
  union { unsigned u; float f; } v;
  v.u = ((unsigned)u) << 16;
  return v.f;
}
__device__ __forceinline__ float4 us4f4(ushort4 u) {
  return make_float4(bf2f(u.x), bf2f(u.y), bf2f(u.z), bf2f(u.w));
}
__device__ __forceinline__ ushort4 f4us4(float4 f) {
  ushort4 o;
  o.x = f2bf(f.x); o.y = f2bf(f.y); o.z = f2bf(f.z); o.w = f2bf(f.w);
  return o;
}
__device__ __forceinline__ float fexp2(float x) {
#if __has_builtin(__builtin_amdgcn_exp2f)
  return __builtin_amdgcn_exp2f(x);
#else
  return exp2f(x);
#endif
}
__device__ __forceinline__ float frcp(float x) {
#if __has_builtin(__builtin_amdgcn_rcpf)
  return __builtin_amdgcn_rcpf(x);
#else
  return 1.0f / x;
#endif
}
__device__ __forceinline__ float fsigmoid(float z) {
  return frcp(1.0f + fexp2(z * -1.4426950408889634f));
}
__device__ __forceinline__ float fexp(float x) { return fexp2(x * 1.4426950408889634f); }

// XCD-affinity swizzle (low 6 bits only)
__device__ __forceinline__ int swz_g(int j) { return (((j >> 3) & 7) << 3) | (j & 7); }

// ---------------------------------------------------------------------------
// D1: per-graph CSR build (blocks FIRST so they start immediately) +
// conversions + weight transposes. grid 3068 x 256.  [verified R4-R11]
// ---------------------------------------------------------------------------
__global__ __launch_bounds__(256) void k_front_csr(
    const float* __restrict__ xd, const float* __restrict__ xq,
    const float* __restrict__ v0, const float* __restrict__ v1,
    const float* __restrict__ v2, ushort* __restrict__ oxd, ushort* __restrict__ oxq,
    ushort* __restrict__ ov0, ushort* __restrict__ ov1, ushort* __restrict__ ov2,
    const float* __restrict__ W1, const float* __restrict__ W2,
    const float* __restrict__ W3, const float* __restrict__ Wn0,
    const float* __restrict__ Wn1, const float* __restrict__ Wn2,
    ushort* __restrict__ o1, ushort* __restrict__ o2, ushort* __restrict__ o3,
    ushort* __restrict__ on0, ushort* __restrict__ on1, ushort* __restrict__ on2,
    const int* __restrict__ src_d, const int* __restrict__ dst_d,
    const int* __restrict__ src_q, const int* __restrict__ dst_q,
    int* __restrict__ cnt_d, int* __restrict__ cnt_q,
    int* __restrict__ rp_d, int* __restrict__ rp_q,
    float* __restrict__ dinv_d, float* __restrict__ dinv_q,
    int* __restrict__ col_d, int* __restrict__ col_q) {
  __shared__ float tile[32][33];
  __shared__ int s_cnt[512];
  __shared__ int s_base[512];
  __shared__ int s_cur[512];
  int blk = blockIdx.x, tid = threadIdx.x;
  if (blk < NB_CSRD) {
    int g = blk;
    const int* dstg = dst_d + g * 4096;
    const int* srcg = src_d + g * 4096;
    int nbase = g * 512;
    s_cnt[tid] = 0; s_cnt[tid + 256] = 0;
    __syncthreads();
    for (int e = tid; e < 4096; e += 256) atomicAdd(&s_cnt[dstg[e] - nbase], 1);
    __syncthreads();
    int c0 = s_cnt[tid], c1 = s_cnt[tid + 256];
    s_base[tid] = c0; s_base[tid + 256] = c1;
    __syncthreads();
    // Hillis-Steele inclusive scan over 512 entries with 256 threads
    for (int off = 1; off < 512; off <<= 1) {
      int a = (tid >= off) ? s_base[tid - off] : 0;
      int b = (tid + 256 >= off) ? s_base[tid + 256 - off] : 0;
      __syncthreads();
      s_base[tid] += a; s_base[tid + 256] += b;
      __syncthreads();
    }
    int e0 = s_base[tid] - c0, e1 = s_base[tid + 256] - c1;
    s_base[tid] = e0; s_base[tid + 256] = e1;
    s_cur[tid] = 0; s_cur[tid + 256] = 0;
    cnt_d[nbase + tid] = c0;
    cnt_d[nbase + tid + 256] = c1;
    rp_d[nbase + tid] = g * 4096 + e0;
    rp_d[nbase + tid + 256] = g * 4096 + e1;
    dinv_d[nbase + tid] = 1.0f / sqrtf((float)(c0 + 1));
    dinv_d[nbase + tid + 256] = 1.0f / sqrtf((float)(c1 + 1));
    __syncthreads();
    for (int e = tid; e < 4096; e += 256) {
      int d = dstg[e] - nbase;
      int p = atomicAdd(&s_cur[d], 1);
      col_d[g * 4096 + s_base[d] + p] = srcg[e];
    }
  } else if (blk < CVT0) {
    int qb = blk - NB_CSRD;
    int lg = tid >> 5, lane32 = tid & 31;
    int g = qb * 8 + lg;
    const int* dstg = dst_q + g * 256;
    const int* srcg = src_q + g * 256;
    int nbase = g * 32;
    s_cnt[tid] = 0;
    __syncthreads();
#pragma unroll
    for (int j = 0; j < 8; ++j)
      atomicAdd(&s_cnt[lg * 32 + (dstg[lane32 + j * 32] - nbase)], 1);
    __syncthreads();
    int v = s_cnt[tid];
    int incl = v;
#pragma unroll
    for (int off = 1; off < 32; off <<= 1) {
      int t = __shfl_up(incl, off, 32);
      if (lane32 >= off) incl += t;
    }
    int excl = incl - v;
    cnt_q[nbase + lane32] = v;
    rp_q[nbase + lane32] = g * 256 + excl;
    dinv_q[nbase + lane32] = 1.0f / sqrtf((float)(v + 1));
    s_base[tid] = excl;
    s_cur[tid] = 0;
    __syncthreads();
#pragma unroll
    for (int j = 0; j < 8; ++j) {
      int e = lane32 + j * 32;
      int d = dstg[e] - nbase;
      int p = atomicAdd(&s_cur[lg * 32 + d], 1);
      col_q[g * 256 + s_base[lg * 32 + d] + p] = srcg[e];
    }
  } else if (blk < TR0) {
    int b2 = blk - CVT0;
    const float* src;
    ushort* dst;
    int i;
    if (b2 < 2048) { src = xd; dst = oxd; i = b2 * 256 + tid; }
    else if (b2 < 2176) { src = xq; dst = oxq; i = (b2 - 2048) * 256 + tid; }
    else if (b2 < 2180) { src = v0; dst = ov0; i = (b2 - 2176) * 256 + tid; }
    else if (b2 < 2184) { src = v1; dst = ov1; i = (b2 - 2180) * 256 + tid; }
    else { src = v2; dst = ov2; i = (b2 - 2184) * 256 + tid; }
    *(ushort4*)(dst + (size_t)i * 4) = f4us4(F4C(src + (size_t)i * 4));
  } else {
    int b5 = blk - TR0;
    const float* in;
    ushort* out;
    int R, C, bt, t;
    if (b5 < 8)        { in = W1;  out = o1;  R = 64;  C = 128; bt = 0; t = b5; }
    else if (b5 < 24)  { in = W2;  out = o2;  R = 128; C = 128; bt = 0; t = b5 - 8; }
    else if (b5 < 40)  { in = W3;  out = o3;  R = 128; C = 128; bt = 0; t = b5 - 24; }
    else if (b5 < 296) { in = Wn0; out = on0; R = 128; C = 128; bt = (b5 - 40) >> 4;  t = (b5 - 40) & 15; }
    else if (b5 < 552) { in = Wn1; out = on1; R = 128; C = 128; bt = (b5 - 296) >> 4; t = (b5 - 296) & 15; }
    else               { in = Wn2; out = on2; R = 128; C = 128; bt = (b5 - 552) >> 4; t = (b5 - 552) & 15; }
    int tilesC = C >> 5;
    int tr = t / tilesC, tc = t - tr * tilesC;
    int tx = tid & 31, ty = tid >> 5;
    const float* ib = in + (size_t)bt * R * C;
    ushort* ob = out + (size_t)bt * R * C;
#pragma unroll
    for (int i = 0; i < 4; ++i)
      tile[ty + i * 8][tx] = ib[(tr * 32 + ty + i * 8) * C + tc * 32 + tx];
    __syncthreads();
#pragma unroll
    for (int i = 0; i < 4; ++i)
      ob[(size_t)(tc * 32 + ty + i * 8) * R + tr * 32 + tx] = f2bf(tile[tx][ty + i * 8]);
  }
}

// ---------------------------------------------------------------------------
// D2: GCN GEMM layer 1 (KD=64). grid 544 x 256. [verified]
// ---------------------------------------------------------------------------
__global__ __launch_bounds__(256) void k_gemm1(
    const ushort* __restrict__ xdbf, const ushort* __restrict__ xqbf,
    const ushort* __restrict__ w1T, const float* __restrict__ dinv_d,
    const float* __restrict__ dinv_q, ushort* __restrict__ htmp) {
  int blk2 = blockIdx.x, tid = threadIdx.x;
  int wave = tid >> 6, lane = tid & 63;
  int col = lane & 15, quad = lane >> 4;
  bool isQ = blk2 >= 512;
  int node0;
  if (isQ) node0 = (blk2 - 512) * 64;
  else node0 = swz_g(blk2) * 512 + (blk2 >> 6) * 64;
  int mloc = node0 + wave * 16;
  const ushort* X = isQ ? xqbf : xdbf;
  const float* dv = isQ ? dinv_q : dinv_d;
  size_t hbase = isQ ? (size_t)cNd : 0;
  floatx4 acc[8];
#pragma unroll
  for (int ct = 0; ct < 8; ++ct)
#pragma unroll
    for (int r = 0; r < 4; ++r) acc[ct][r] = 0.0f;
#pragma unroll
  for (int kc = 0; kc < 2; ++kc) {
    bf16x8 a = *(const bf16x8*)(X + (size_t)(mloc + col) * 64 + kc * 32 + quad * 8);
#pragma unroll
    for (int ct = 0; ct < 8; ++ct) {
      bf16x8 b = *(const bf16x8*)(w1T + (size_t)(ct * 16 + col) * 64 + kc * 32 + quad * 8);
      acc[ct] = __builtin_amdgcn_mfma_f32_16x16x32_bf16(a, b, acc[ct], 0, 0, 0);
    }
  }
  float sc[4];
#pragma unroll
  for (int r = 0; r < 4; ++r) sc[r] = dv[mloc + quad * 4 + r];
#pragma unroll
  for (int ct = 0; ct < 8; ++ct)
#pragma unroll
    for (int r = 0; r < 4; ++r)
      htmp[(hbase + mloc + quad * 4 + r) * 128 + ct * 16 + col] = f2bf(acc[ct][r] * sc[r]);
}

// ---------------------------------------------------------------------------
// GCN aggregate (byte-identical to R0's verified gmn_gather_merged).
// grid 4352 x 256.
// ---------------------------------------------------------------------------
__global__ __launch_bounds__(256) void gmn_gather_merged(
    const ushort* __restrict__ htmp, const int* __restrict__ rp_d,
    const int* __restrict__ cnt_d, const int* __restrict__ col_d,
    const float* __restrict__ dinv_d, const int* __restrict__ rp_q,
    const int* __restrict__ cnt_q, const int* __restrict__ col_q,
    const float* __restrict__ dinv_q, const float* __restrict__ bias,
    ushort* __restrict__ dbf, ushort* __restrict__ qbf) {
  int blk = blockIdx.x, tid = threadIdx.x;
  bool isQ = blk >= 4096;
  int node;
  if (isQ) {
    int j = blk - 4096;
    node = swz_g(j) * 32 + (j >> 6) * 8 + (tid >> 5);
  } else {
    node = swz_g(blk) * 512 + (blk >> 6) * 8 + (tid >> 5);
  }
  int l = tid & 31;
  const ushort* hs = htmp + (isQ ? (size_t)cNd * 128 : 0);
  const int* rp = isQ ? rp_q : rp_d;
  const int* cnt = isQ ? cnt_q : cnt_d;
  const int* col = isQ ? col_q : col_d;
  const float* dinv = isQ ? dinv_q : dinv_d;
  ushort* outp = isQ ? qbf : dbf;
  int c = cnt[node], s0 = rp[node];
  float dt = dinv[node];
  float4 acc = us4f4(*(const ushort4*)(hs + (size_t)node * 128 + l * 4));
  int cm = c < 32 ? c : 32;
  for (int j0 = 0; j0 < cm; j0 += 8) {
    int ss[8];
    ushort4 v[8];
#pragma unroll
    for (int t = 0; t < 8; ++t) {
      int jj = j0 + t;
      ss[t] = (jj < cm) ? col[s0 + jj] : -1;
    }
#pragma unroll
    for (int t = 0; t < 8; ++t)
      if (ss[t] >= 0) v[t] = *(const ushort4*)(hs + (size_t)ss[t] * 128 + l * 4);
#pragma unroll
    for (int t = 0; t < 8; ++t) {
      if (ss[t] >= 0) {
        float4 f = us4f4(v[t]);
        acc.x += f.x; acc.y += f.y; acc.z += f.z; acc.w += f.w;
      }
    }
  }
  for (int j = 32; j < c; ++j) {
    int s = col[s0 + j];
    float4 f = us4f4(*(const ushort4*)(hs + (size_t)s * 128 + l * 4));
    acc.x += f.x; acc.y += f.y; acc.z += f.z; acc.w += f.w;
  }
  float4 bv = F4C(bias + l * 4);
  float4 r;
  r.x = fmaxf(acc.x * dt + bv.x, 0.0f);
  r.y = fmaxf(acc.y * dt + bv.y, 0.0f);
  r.z = fmaxf(acc.z * dt + bv.z, 0.0f);
  r.w = fmaxf(acc.w * dt + bv.w, 0.0f);
  *(ushort4*)(outp + (size_t)node * 128 + l * 4) = f4us4(r);
}

// ---------------------------------------------------------------------------
// qW prep (byte-identical to R0's verified gmn_qw): qW[b,k] = q[b] @ Wn[k].
// grid 1024 x 256.
// ---------------------------------------------------------------------------
__global__ __launch_bounds__(256) void gmn_qw(const ushort* __restrict__ qbf,
                                              const ushort* __restrict__ wnT,
                                              ushort* __restrict__ qw) {
  int blk = blockIdx.x, tid = threadIdx.x;
  int wave = tid >> 6, lane = tid & 63;
  int col = lane & 15, quad = lane >> 4;
  int b = swz_g(blk), k = blk >> 6;
  int et0 = wave * 2;
  floatx4 acc[2][2];
#pragma unroll
  for (int qt = 0; qt < 2; ++qt)
#pragma unroll
    for (int ei = 0; ei < 2; ++ei)
#pragma unroll
      for (int r = 0; r < 4; ++r) acc[qt][ei][r] = 0.0f;
#pragma unroll
  for (int kc = 0; kc < 4; ++kc) {
    bf16x8 a0 = *(const bf16x8*)(qbf + (size_t)(b * 32 + col) * 128 + kc * 32 + quad * 8);
    bf16x8 a1 = *(const bf16x8*)(qbf + (size_t)(b * 32 + 16 + col) * 128 + kc * 32 + quad * 8);
#pragma unroll
    for (int ei = 0; ei < 2; ++ei) {
      bf16x8 bf = *(const bf16x8*)(wnT + (size_t)(k * 128 + (et0 + ei) * 16 + col) * 128 +
                                   kc * 32 + quad * 8);
      acc[0][ei] = __builtin_amdgcn_mfma_f32_16x16x32_bf16(a0, bf, acc[0][ei], 0, 0, 0);
      acc[1][ei] = __builtin_amdgcn_mfma_f32_16x16x32_bf16(a1, bf, acc[1][ei], 0, 0, 0);
    }
  }
#pragma unroll
  for (int qt = 0; qt < 2; ++qt)
#pragma unroll
    for (int ei = 0; ei < 2; ++ei)
#pragma unroll
      for (int r = 0; r < 4; ++r)
        qw[((size_t)(b * 16 + k) << 12) + (qt * 16 + quad * 4 + r) * 128 +
           (et0 + ei) * 16 + col] = f2bf(acc[qt][ei][r]);
}

// ---------------------------------------------------------------------------
// Merged dispatch (byte-identical to R0/R8's verified k_level_gemm): fused NTN
// level reading qw from GLOBAL (no k-loop barriers, 4-s ILP) [blk<128] +
// next-layer GCN GEMM KD=128 [blk in [128,400)]. __launch_bounds__(512,2).
// ---------------------------------------------------------------------------
__global__ __launch_bounds__(512, 2) void k_level_gemm(
    const ushort* __restrict__ qbf, const ushort* __restrict__ dbf,
    const ushort* __restrict__ qw, const ushort* __restrict__ vnbf,
    const float* __restrict__ bn, const float* __restrict__ cw,
    const float* __restrict__ w_end, const float* __restrict__ b_end,
    int o1, int o2, int hasF, int do_sm, int mode, int widx,
    float* __restrict__ accb, float* __restrict__ out,
    const ushort* __restrict__ gWT, const float* __restrict__ dinv_d,
    const float* __restrict__ dinv_q, ushort* __restrict__ htmp) {
  __shared__ float s_ld[16 * LD_STRIDE];
  __shared__ float s_lq[16 * 16];
  __shared__ float s_red[16 * 8];
  int tid = threadIdx.x;
  int wave = tid >> 6, lane = tid & 63;
  int col = lane & 15, quad = lane >> 4;

  if (blockIdx.x >= 128) {  // ---------------- GEMM KD=128 section ----------
    int gblk = blockIdx.x - 128;  // [0,272): data [0,256), query [256,272)
    bool isQ = gblk >= 256;
    int node0;
    if (isQ) node0 = (gblk - 256) * 128;
    else node0 = swz_g(gblk) * 512 + (gblk >> 6) * 128;
    int mloc = node0 + wave * 16;
    const ushort* X = isQ ? qbf : dbf;
    const float* dv = isQ ? dinv_q : dinv_d;
    size_t hbase = isQ ? (size_t)cNd : 0;
    floatx4 acc[8];
#pragma unroll
    for (int ct = 0; ct < 8; ++ct)
#pragma unroll
      for (int r = 0; r < 4; ++r) acc[ct][r] = 0.0f;
#pragma unroll
    for (int kc = 0; kc < 4; ++kc) {
      bf16x8 a = *(const bf16x8*)(X + (size_t)(mloc + col) * 128 + kc * 32 + quad * 8);
#pragma unroll
      for (int ct = 0; ct < 8; ++ct) {
        bf16x8 b = *(const bf16x8*)(gWT + (size_t)(ct * 16 + col) * 128 + kc * 32 + quad * 8);
        acc[ct] = __builtin_amdgcn_mfma_f32_16x16x32_bf16(a, b, acc[ct], 0, 0, 0);
      }
    }
    float sc[4];
#pragma unroll
    for (int r = 0; r < 4; ++r) sc[r] = dv[mloc + quad * 4 + r];
#pragma unroll
    for (int ct = 0; ct < 8; ++ct)
#pragma unroll
      for (int r = 0; r < 4; ++r)
        htmp[(hbase + mloc + quad * 4 + r) * 128 + ct * 16 + col] = f2bf(acc[ct][r] * sc[r]);
    return;
  }

  // ---------------- fused level section ------------------------------------
  int b = swz_g(blockIdx.x & 63);
  int qh = blockIdx.x >> 6;
  int n0 = wave * 64;

  bf16x8 bfr[4][4];
#pragma unroll
  for (int s = 0; s < 4; ++s)
#pragma unroll
    for (int kc = 0; kc < 4; ++kc)
      bfr[s][kc] = *(const bf16x8*)(dbf + ((size_t)(b * 512 + n0 + s * 16 + col) << 7) +
                                    kc * 32 + quad * 8);
  bf16x8 aq[4];
#pragma unroll
  for (int kc = 0; kc < 4; ++kc)
    aq[kc] = *(const bf16x8*)(qbf + (size_t)(b * 32 + qh * 16 + col) * 128 +
                              kc * 32 + quad * 8);

  floatx4 att[4];
#pragma unroll
  for (int s = 0; s < 4; ++s)
#pragma unroll
    for (int r = 0; r < 4; ++r) att[s][r] = 0.0f;
#pragma unroll
  for (int kc = 0; kc < 4; ++kc)
#pragma unroll
    for (int s = 0; s < 4; ++s)
      att[s] = __builtin_amdgcn_mfma_f32_16x16x32_bf16(aq[kc], bfr[s][kc], att[s], 0, 0, 0);
  const float sc = 0.088388347648318440550f;
#pragma unroll
  for (int s = 0; s < 4; ++s)
#pragma unroll
    for (int r = 0; r < 4; ++r) att[s][r] *= sc;

  {
    bf16x8 vn2[4];
#pragma unroll
    for (int kc = 0; kc < 4; ++kc)
      vn2[kc] = *(const bf16x8*)(vnbf + col * 256 + 128 + kc * 32 + quad * 8);
#pragma unroll
    for (int s = 0; s < 4; ++s) {
      floatx4 lda;
#pragma unroll
      for (int r = 0; r < 4; ++r) lda[r] = 0.0f;
#pragma unroll
      for (int kc = 0; kc < 4; ++kc)
        lda = __builtin_amdgcn_mfma_f32_16x16x32_bf16(bfr[s][kc], vn2[kc], lda, 0, 0, 0);
#pragma unroll
      for (int r = 0; r < 4; ++r)
        s_ld[col * LD_STRIDE + n0 + s * 16 + quad * 4 + r] = lda[r];
    }
  }
  if (wave == 0) {
    bf16x8 vn1[4];
#pragma unroll
    for (int kc = 0; kc < 4; ++kc)
      vn1[kc] = *(const bf16x8*)(vnbf + col * 256 + kc * 32 + quad * 8);
    floatx4 lqa;
#pragma unroll
    for (int r = 0; r < 4; ++r) lqa[r] = 0.0f;
#pragma unroll
    for (int kc = 0; kc < 4; ++kc)
      lqa = __builtin_amdgcn_mfma_f32_16x16x32_bf16(aq[kc], vn1[kc], lqa, 0, 0, 0);
#pragma unroll
    for (int r = 0; r < 4; ++r) s_lq[col * 16 + quad * 4 + r] = lqa[r];
  }
  __syncthreads();

  float red[4], M[4];
#pragma unroll
  for (int r = 0; r < 4; ++r) {
    float m = fmaxf(fmaxf(att[0][r], att[1][r]), fmaxf(att[2][r], att[3][r]));
#pragma unroll
    for (int o = 1; o < 16; o <<= 1) m = fmaxf(m, __shfl_xor(m, o, 64));
    red[r] = m;
  }
  if (col == 0)
#pragma unroll
    for (int r = 0; r < 4; ++r) s_red[(quad * 4 + r) * 8 + wave] = red[r];
  __syncthreads();
#pragma unroll
  for (int r = 0; r < 4; ++r) {
    float m = s_red[(quad * 4 + r) * 8];
#pragma unroll
    for (int w = 1; w < 8; ++w) m = fmaxf(m, s_red[(quad * 4 + r) * 8 + w]);
    M[r] = m;
  }
  __syncthreads();
#pragma unroll
  for (int s = 0; s < 4; ++s)
#pragma unroll
    for (int r = 0; r < 4; ++r) att[s][r] = fexp(att[s][r] - M[r]);
#pragma unroll
  for (int r = 0; r < 4; ++r) {
    float m = att[0][r] + att[1][r] + att[2][r] + att[3][r];
#pragma unroll
    for (int o = 1; o < 16; o <<= 1) m += __shfl_xor(m, o, 64);
    red[r] = m;
  }
  if (col == 0)
#pragma unroll
    for (int r = 0; r < 4; ++r) s_red[(quad * 4 + r) * 8 + wave] = red[r];
  __syncthreads();
#pragma unroll
  for (int r = 0; r < 4; ++r) {
    float m = s_red[(quad * 4 + r) * 8];
#pragma unroll
    for (int w = 1; w < 8; ++w) m += s_red[(quad * 4 + r) * 8 + w];
    M[r] = frcp(m);
  }
  __syncthreads();
#pragma unroll
  for (int s = 0; s < 4; ++s)
#pragma unroll
    for (int r = 0; r < 4; ++r) att[s][r] *= M[r];

  floatx4 eacc[4], facc[4];
#pragma unroll
  for (int s = 0; s < 4; ++s)
#pragma unroll
    for (int r = 0; r < 4; ++r) { eacc[s][r] = 0.0f; facc[s][r] = 0.0f; }

#pragma unroll 4
  for (int k = 0; k < 16; ++k) {
    const ushort* qk = qw + ((size_t)(b * 16 + k) << 12) + (qh * 16 + col) * 128 + quad * 8;
    bf16x8 a0 = *(const bf16x8*)(qk);
    bf16x8 a1 = *(const bf16x8*)(qk + 32);
    bf16x8 a2 = *(const bf16x8*)(qk + 64);
    bf16x8 a3 = *(const bf16x8*)(qk + 96);
    floatx4 bil[4];
#pragma unroll
    for (int s = 0; s < 4; ++s) {
#pragma unroll
      for (int r = 0; r < 4; ++r) bil[s][r] = 0.0f;
      bil[s] = __builtin_amdgcn_mfma_f32_16x16x32_bf16(a0, bfr[s][0], bil[s], 0, 0, 0);
      bil[s] = __builtin_amdgcn_mfma_f32_16x16x32_bf16(a1, bfr[s][1], bil[s], 0, 0, 0);
      bil[s] = __builtin_amdgcn_mfma_f32_16x16x32_bf16(a2, bfr[s][2], bil[s], 0, 0, 0);
      bil[s] = __builtin_amdgcn_mfma_f32_16x16x32_bf16(a3, bfr[s][3], bil[s], 0, 0, 0);
    }
    float bnk = bn[k], cwk = cw[k];
    float wkk = 0.0f;
    if (hasF) {
      wkk = w_end[o1 + k];
      if (o2 >= 0) wkk += w_end[o2 + k];
    }
    float lqv[4];
#pragma unroll
    for (int r = 0; r < 4; ++r) lqv[r] = s_lq[k * 16 + quad * 4 + r] + bnk;
#pragma unroll
    for (int s = 0; s < 4; ++s) {
      float ldv = s_ld[k * LD_STRIDE + n0 + s * 16 + col];
#pragma unroll
      for (int r = 0; r < 4; ++r) {
        float sg = fsigmoid(bil[s][r] + lqv[r] + ldv);
        eacc[s][r] += cwk * sg;
        facc[s][r] += wkk * sg;
      }
    }
  }

#pragma unroll
  for (int s = 0; s < 4; ++s)
#pragma unroll
    for (int r = 0; r < 4; ++r) {
      eacc[s][r] *= att[s][r];
      facc[s][r] *= att[s][r];
    }
  if (do_sm) {
#pragma unroll
    for (int r = 0; r < 4; ++r) {
      float m = fmaxf(fmaxf(eacc[0][r], eacc[1][r]), fmaxf(eacc[2][r], eacc[3][r]));
#pragma unroll
      for (int o = 1; o < 16; o <<= 1) m = fmaxf(m, __shfl_xor(m, o, 64));
      red[r] = m;
    }
    if (col == 0)
#pragma unroll
      for (int r = 0; r < 4; ++r) s_red[(quad * 4 + r) * 8 + wave] = red[r];
    __syncthreads();
#pragma unroll
    for (int r = 0; r < 4; ++r) {
      float m = s_red[(quad * 4 + r) * 8];
#pragma unroll
      for (int w = 1; w < 8; ++w) m = fmaxf(m, s_red[(quad * 4 + r) * 8 + w]);
      M[r] = m;
    }
    __syncthreads();
#pragma unroll
    for (int s = 0; s < 4; ++s)
#pragma unroll
      for (int r = 0; r < 4; ++r) eacc[s][r] = fexp(eacc[s][r] - M[r]);
#pragma unroll
    for (int r = 0; r < 4; ++r) {
      float m = eacc[0][r] + eacc[1][r] + eacc[2][r] + eacc[3][r];
#pragma unroll
      for (int o = 1; o < 16; o <<= 1) m += __shfl_xor(m, o, 64);
      red[r] = m;
    }
    if (col == 0)
#pragma unroll
      for (int r = 0; r < 4; ++r) s_red[(quad * 4 + r) * 8 + wave] = red[r];
    __syncthreads();
#pragma unroll
    for (int r = 0; r < 4; ++r) {
      float m = s_red[(quad * 4 + r) * 8];
#pragma unroll
      for (int w = 1; w < 8; ++w) m += s_red[(quad * 4 + r) * 8 + w];
      M[r] = frcp(m);
    }
    __syncthreads();
#pragma unroll
    for (int s = 0; s < 4; ++s)
#pragma unroll
      for (int r = 0; r < 4; ++r) eacc[s][r] *= M[r];
  }
  float w = w_end[widx];
#pragma unroll
  for (int s = 0; s < 4; ++s)
#pragma unroll
    for (int r = 0; r < 4; ++r) eacc[s][r] = w * eacc[s][r] + (hasF ? facc[s][r] : 0.0f);

  if (mode == 0) {
#pragma unroll
    for (int s = 0; s < 4; ++s)
#pragma unroll
      for (int r = 0; r < 4; ++r)
        accb[((size_t)(b * 32 + qh * 16 + quad * 4 + r) << 9) + n0 + s * 16 + col] =
            eacc[s][r];
  } else if (mode == 1) {
#pragma unroll
    for (int s = 0; s < 4; ++s)
#pragma unroll
      for (int r = 0; r < 4; ++r)
        accb[((size_t)(b * 32 + qh * 16 + quad * 4 + r) << 9) + n0 + s * 16 + col] +=
            eacc[s][r];
  } else {
    float be = b_end[0];
#pragma unroll
    for (int s = 0; s < 4; ++s)
#pragma unroll
      for (int r = 0; r < 4; ++r)
        eacc[s][r] += accb[((size_t)(b * 32 + qh * 16 + quad * 4 + r) << 9) +
                           n0 + s * 16 + col] + be;
#pragma unroll
    for (int r = 0; r < 4; ++r) {
      float m = fmaxf(fmaxf(eacc[0][r], eacc[1][r]), fmaxf(eacc[2][r], eacc[3][r]));
#pragma unroll
      for (int o = 1; o < 16; o <<= 1) m = fmaxf(m, __shfl_xor(m, o, 64));
      red[r] = m;
    }
    if (col == 0)
#pragma unroll
      for (int r = 0; r < 4; ++r) s_red[(quad * 4 + r) * 8 + wave] = red[r];
    __syncthreads();
#pragma unroll
    for (int r = 0; r < 4; ++r) {
      float m = s_red[(quad * 4 + r) * 8];
#pragma unroll
      for (int w2 = 1; w2 < 8; ++w2) m = fmaxf(m, s_red[(quad * 4 + r) * 8 + w2]);
      M[r] = m;
    }
    __syncthreads();
#pragma unroll
    for (int s = 0; s < 4; ++s)
#pragma unroll
      for (int r = 0; r < 4; ++r) eacc[s][r] = fexp(eacc[s][r] - M[r]);
#pragma unroll
    for (int r = 0; r < 4; ++r) {
      float m = eacc[0][r] + eacc[1][r] + eacc[2][r] + eacc[3][r];
#pragma unroll
      for (int o = 1; o < 16; o <<= 1) m += __shfl_xor(m, o, 64);
      red[r] = m;
    }
    if (col == 0)
#pragma unroll
      for (int r = 0; r < 4; ++r) s_red[(quad * 4 + r) * 8 + wave] = red[r];
    __syncthreads();
#pragma unroll
    for (int r = 0; r < 4; ++r) {
      float m = s_red[(quad * 4 + r) * 8];
#pragma unroll
      for (int w2 = 1; w2 < 8; ++w2) m += s_red[(quad * 4 + r) * 8 + w2];
      M[r] = frcp(m);
    }
#pragma unroll
    for (int s = 0; s < 4; ++s)
#pragma unroll
      for (int r = 0; r < 4; ++r)
        out[((size_t)(b * 32 + qh * 16 + quad * 4 + r) << 9) + n0 + s * 16 + col] =
            eacc[s][r] * M[r];
  }
}

// ---------------------------------------------------------------------------
// Host orchestration — 11 dispatches:
// front_csr, gemm1, [gather, qw, level(+gemm)] x3
// ---------------------------------------------------------------------------
extern "C" void kernel_launch(void* const* d_in, const int* in_sizes, int n_in,
                              void* d_out, int out_size, void* d_ws, size_t ws_size,
                              hipStream_t stream) {
  (void)in_sizes; (void)n_in; (void)out_size; (void)ws_size;
  const float* x_d = (const float*)d_in[0];
  const float* x_q = (const float*)d_in[1];
  const int* ei_d = (const int*)d_in[2];
  const int* ei_q = (const int*)d_in[3];
  const float* W1 = (const float*)d_in[6];
  const float* b1 = (const float*)d_in[7];
  const float* W2 = (const float*)d_in[8];
  const float* b2 = (const float*)d_in[9];
  const float* W3 = (const float*)d_in[10];
  const float* b3 = (const float*)d_in[11];
  const float* Wn[3] = {(const float*)d_in[12], (const float*)d_in[17], (const float*)d_in[22]};
  const float* Vn[3] = {(const float*)d_in[13], (const float*)d_in[18], (const float*)d_in[23]};
  const float* bn[3] = {(const float*)d_in[14], (const float*)d_in[19], (const float*)d_in[24]};
  const float* cw[3] = {(const float*)d_in[15], (const float*)d_in[20], (const float*)d_in[25]};
  const float* w_end = (const float*)d_in[27];
  const float* b_end = (const float*)d_in[28];
  float* out = (float*)d_out;

  char* wsp = (char*)d_ws;
  auto alloc = [&](size_t nbytes) {
    void* p = (void*)wsp;
    wsp += (nbytes + 255) & ~(size_t)255;
    return p;
  };
  int* cnt_d = (int*)alloc(cNd * 4);
  int* cnt_q = (int*)alloc(cNq * 4);
  float* dinv_d = (float*)alloc(cNd * 4);
  float* dinv_q = (float*)alloc(cNq * 4);
  int* rp_d = (int*)alloc(cNd * 4);
  int* rp_q = (int*)alloc(cNq * 4);
  int* col_d = (int*)alloc((size_t)cEd * 4);
  int* col_q = (int*)alloc((size_t)cEq * 4);
  ushort* xdbf = (ushort*)alloc((size_t)cNd * 64 * 2);
  ushort* xqbf = (ushort*)alloc((size_t)cNq * 64 * 2);
  ushort* w1T = (ushort*)alloc(128 * 64 * 2);
  ushort* w2T = (ushort*)alloc(128 * 128 * 2);
  ushort* w3T = (ushort*)alloc(128 * 128 * 2);
  ushort* wnT[3];
  for (int l = 0; l < 3; ++l) wnT[l] = (ushort*)alloc((size_t)16 * 128 * 128 * 2);
  ushort* vnbf[3];
  for (int l = 0; l < 3; ++l) vnbf[l] = (ushort*)alloc(16 * 256 * 2);
  ushort* htmp = (ushort*)alloc((size_t)(cNd + cNq) * 128 * 2);
  ushort* dbf = (ushort*)alloc((size_t)cNd * 128 * 2);
  ushort* qbf[3];
  for (int l = 0; l < 3; ++l) qbf[l] = (ushort*)alloc((size_t)cNq * 128 * 2);
  float* accb = (float*)alloc((size_t)cB * cNQ * cND * 4);
  ushort* qwbuf = (ushort*)alloc((size_t)cB * 16 * 32 * 128 * 2);

  const int* src_d = ei_d;
  const int* dst_d = ei_d + cEd;
  const int* src_q = ei_q;
  const int* dst_q = ei_q + cEq;

  // D1: CSR build (first blocks) + conversions + transposes (no memset needed)
  k_front_csr<<<TR0 + NB_T2BF, 256, 0, stream>>>(
      x_d, x_q, Vn[0], Vn[1], Vn[2], xdbf, xqbf, vnbf[0], vnbf[1], vnbf[2], W1, W2,
      W3, Wn[0], Wn[1], Wn[2], w1T, w2T, w3T, wnT[0], wnT[1], wnT[2],
      src_d, dst_d, src_q, dst_q, cnt_d, cnt_q, rp_d, rp_q, dinv_d, dinv_q,
      col_d, col_q);

  // D2: GEMM layer 1
  k_gemm1<<<544, 256, 0, stream>>>(xdbf, xqbf, w1T, dinv_d, dinv_q, htmp);

  const float* bias[3] = {b1, b2, b3};
  const ushort* nextWT[3] = {w2T, w3T, nullptr};
  const int o1s[3] = {0, 19, 3};
  const int o2s[3] = {-1, -1, 35};
  const int hasF[3] = {0, 1, 1};
  const int dosms[3] = {1, 0, 1};
  const int modes[3] = {0, 1, 2};

  for (int l = 0; l < 3; ++l) {
    // gather layer l -> dbf, qbf[l]
    gmn_gather_merged<<<(cNd + cNq) / 8, 256, 0, stream>>>(
        htmp, rp_d, cnt_d, col_d, dinv_d, rp_q, cnt_q, col_q, dinv_q, bias[l], dbf,
        qbf[l]);
    // qW for level l (separate, massively parallel — the verified fast path)
    gmn_qw<<<1024, 256, 0, stream>>>(qbf[l], wnT[l], qwbuf);
    // fused level l (global qw reads, barrier-free k-loop) + GEMM for layer l+1
    int grid = (l < 2) ? (128 + 272) : 128;
    k_level_gemm<<<grid, 512, 0, stream>>>(
        qbf[l], dbf, qwbuf, vnbf[l], bn[l], cw[l], w_end, b_end, o1s[l], o2s[l],
        hasF[l], dosms[l], modes[l], l, accb, out, nextWT[l], dinv_d, dinv_q, htmp);
  }
}